// Round 7
// baseline (378.700 us; speedup 1.0000x reference)
//
#include <hip/hip_runtime.h>
#include <hip/hip_bf16.h>
#include <math.h>

// ============================================================================
// SelfAttention B=4 S=4096 D=512, fp32 in/out, bf16 MFMA internally.
//
// R7 changes vs R6 (R6 post-mortem: hoisting K-loop VALU made all pipes idle
// <21% -> kernels are latency-bound on the barrier-drain chain; the in-loop
// address VALU of R5 was useful overlap. Lever = resident waves/CU):
//  - Revert R6's hoist/unroll; back to R5's runtime K-loop + in-loop address
//    computation (R5 was 10-27% faster per kernel).
//  - Keep R6's padded C-tile (CP = TN+8; R5's 2.1M conflicts -> 0.5M).
//  - 512-thread blocks, 8 waves as 2(M)x4(N): wave tile halves in N, acc
//    VGPRs halve (32/16 fp32), ~100 regs/wave -> 2 blocks x 8 waves =
//    16 waves/CU (vs 12), with 2x work per barrier instance.
//
// GEMM core (m97 structure): TMxTN tile, BK=64, global_load_lds width=16,
// XOR chunk swizzle (chunk ^= row&7) on the staged GLOBAL address so the
// hardware's base+lane*16 LDS write lands global chunk g at physical g^(r&7);
// readers XOR the same way. Epilogue via padded LDS C-tile, 16B stores.
// Q pre-scaled by 1/sqrt(512)*log2(e) => EXP epilogue = one v_exp_f32/elem.
// Softmax needs no max-subtraction: |score| <= |q||k|/sqrt(512) ~ 7.5.
// ============================================================================

typedef __bf16 bfx8 __attribute__((ext_vector_type(8)));
typedef __bf16 bfx4 __attribute__((ext_vector_type(4)));
typedef float  fx4  __attribute__((ext_vector_type(4)));

#define HID   512
#define NBATCH 4
#define SEQ   4096
#define MROWS (NBATCH * SEQ)

#if __has_builtin(__builtin_amdgcn_exp2f)
#define EXPFN(x) __builtin_amdgcn_exp2f(x)
#define QSCALE 0.06375871589f   /* (1/sqrt(512)) * log2(e) */
#else
#define EXPFN(x) __expf(x)
#define QSCALE 0.04419417382f   /* 1/sqrt(512) */
#endif

constexpr int MODE_QKV = 0;  // C0=Q(bf16,scaled) C1=K(bf16) C2=Vt(bf16,transposed)
constexpr int MODE_EXP = 2;  // C0 bf16 = exp2(acc), atomic rowsum
constexpr int MODE_DIV = 3;  // C0 fp32 = acc / rowsum[m]

// ---------------------------------------------------------------------------
__device__ __forceinline__ void gload_lds16(const __bf16* gsrc, __bf16* ldst) {
  __builtin_amdgcn_global_load_lds(
      (const __attribute__((address_space(1))) unsigned int*)gsrc,
      (__attribute__((address_space(3))) unsigned int*)ldst,
      16, 0, 0);
}

// ---------------------------------------------------------------------------
__global__ void prep_x_kernel(const float* __restrict__ X, __bf16* __restrict__ Xb) {
  int i = (blockIdx.x * 256 + threadIdx.x) * 4;
  const float4 v = *(const float4*)(X + i);
  bfx4 o;
  o[0] = (__bf16)v.x; o[1] = (__bf16)v.y; o[2] = (__bf16)v.z; o[3] = (__bf16)v.w;
  *(bfx4*)(Xb + i) = o;
}

__global__ void prep_w_kernel(const float* __restrict__ Wq, const float* __restrict__ Wk,
                              const float* __restrict__ Wv, __bf16* __restrict__ Wt) {
  int id  = blockIdx.x * 256 + threadIdx.x;   // 0 .. 3*512*512-1
  int g   = id >> 18;
  int rem = id & ((1 << 18) - 1);
  int i   = rem >> 9;          // input dim (row of W)
  int o   = rem & 511;         // output dim (col of W) -- coalesced read
  const float* W = (g == 0) ? Wq : ((g == 1) ? Wk : Wv);
  Wt[(g << 18) + (o << 9) + i] = (__bf16)W[rem];
}

// ---------------------------------------------------------------------------
// C[M,N] = A[M,K] @ B[N,K]^T (+ mode epilogue).  TMxTN tile, BK=64,
// 512 threads = 8 waves as 2(M)x4(N); wave tile (TM/2)x(TN/4).
template <int MODE, int TM, int TN>
__global__ __launch_bounds__(512)
void gemm_bt(const __bf16* __restrict__ A, const __bf16* __restrict__ B,
             void* __restrict__ C0v, void* __restrict__ C1v, void* __restrict__ C2v,
             const float* __restrict__ b0, const float* __restrict__ b1,
             const float* __restrict__ b2, float* __restrict__ rowsum,
             int lda, int ldb, int ldc, int K_,
             long sA, long sB, long sC, int sR) {
  constexpr int MT = TM / 32;   // 16-row mfma tiles per wave (M), wave tile TM/2
  constexpr int NT = TN / 64;   // 16-col mfma tiles per wave (N), wave tile TN/4
  constexpr int CP = TN + 8;    // padded C-tile stride (bank de-alias)
  constexpr int ABE = (TM + TN) * 64;                              // staging elems
  constexpr int CTE = (MODE == MODE_DIV) ? TM * CP * 2 : TM * CP;  // bf16 units
  constexpr int LDSN = (ABE > CTE) ? ABE : CTE;
  __shared__ __bf16 L[LDSN];
  __bf16* As = L;
  __bf16* Bs = L + TM * 64;

  const int z = blockIdx.z;
  A += (long)z * sA;
  B += (long)z * sB;

  const int tid  = threadIdx.x;
  const int lane = tid & 63;
  const int w    = tid >> 6;        // 0..7
  const int wm   = w >> 2, wn = w & 3;
  const int lm   = lane & 15, lq = lane >> 4;

  const int row0 = blockIdx.y * TM;
  const int col0 = blockIdx.x * TN;

  const __bf16* Ag = A + (long)row0 * lda;
  const __bf16* Bg = B + (long)col0 * ldb;

  fx4 acc[MT][NT] = {};

  for (int kt = 0; kt < K_; kt += 64) {
    __syncthreads();  // previous compute done reading LDS
#pragma unroll
    for (int it = 0; it < TM / 64; ++it) {
      int s = it * 512 + tid;
      int r = s >> 3, c = ((s & 7) ^ (r & 7)) << 3;
      gload_lds16(Ag + (long)r * lda + kt + c, As + it * 4096 + w * 512);
    }
#pragma unroll
    for (int it = 0; it < TN / 64; ++it) {
      int s = it * 512 + tid;
      int r = s >> 3, c = ((s & 7) ^ (r & 7)) << 3;
      gload_lds16(Bg + (long)r * ldb + kt + c, Bs + it * 4096 + w * 512);
    }
    __syncthreads();  // drains vmcnt(0) + barrier
#pragma unroll
    for (int kk = 0; kk < 2; ++kk) {
      bfx8 af[MT], bfr[NT];
#pragma unroll
      for (int t = 0; t < MT; ++t) {
        int ra = wm * (TM / 2) + t * 16 + lm;
        af[t] = *(const bfx8*)(As + ra * 64 + (((kk * 4 + lq) ^ (ra & 7)) << 3));
      }
#pragma unroll
      for (int t = 0; t < NT; ++t) {
        int rb = wn * (TN / 4) + t * 16 + lm;
        bfr[t] = *(const bfx8*)(Bs + rb * 64 + (((kk * 4 + lq) ^ (rb & 7)) << 3));
      }
#pragma unroll
      for (int mt = 0; mt < MT; ++mt)
#pragma unroll
        for (int nt = 0; nt < NT; ++nt)
          acc[mt][nt] = __builtin_amdgcn_mfma_f32_16x16x32_bf16(af[mt], bfr[nt],
                                                                acc[mt][nt], 0, 0, 0);
    }
  }

  // ---- epilogue ----  C/D layout: col = lane&15, row = (lane>>4)*4 + i
  const int lr0 = wm * (TM / 2);   // + mt*16 + lq*4 + i
  const int lc0 = wn * (TN / 4);   // + nt*16 + lm

  __syncthreads();  // all waves done reading As/Bs; LDS now reusable as C-tile

  if constexpr (MODE == MODE_QKV) {
    const int g   = col0 >> 9;            // 0=Q 1=K 2=V (block-uniform)
    const int gc  = col0 & 511;           // col within the g-th output
    const float* bias = (g == 0) ? b0 : ((g == 1) ? b1 : b2);
    float bvv[NT];
#pragma unroll
    for (int nt = 0; nt < NT; ++nt) bvv[nt] = bias[gc + lc0 + nt * 16 + lm];

    if (g < 2) {  // Q (pre-scaled) / K: LDS C-tile roundtrip, vectorized store
      __bf16* Ct = L;
#pragma unroll
      for (int mt = 0; mt < MT; ++mt)
#pragma unroll
        for (int nt = 0; nt < NT; ++nt)
#pragma unroll
          for (int i = 0; i < 4; ++i) {
            float v = acc[mt][nt][i] + bvv[nt];
            if (g == 0) v *= QSCALE;
            Ct[(lr0 + mt * 16 + lq * 4 + i) * CP + lc0 + nt * 16 + lm] = (__bf16)v;
          }
      __syncthreads();
      __bf16* C = (g == 0) ? (__bf16*)C0v : (__bf16*)C1v;
#pragma unroll
      for (int j = 0; j < TM * TN / 4096; ++j) {
        int s = j * 512 + tid;
        int off = s * 8;
        int r = off / TN, c = off % TN;
        *(bfx8*)(C + (long)(row0 + r) * ldc + gc + c) = *(const bfx8*)(Ct + r * CP + c);
      }
    } else {  // V, transposed: Vt[b][hid][seq], 4 consecutive seq -> 8B store
      __bf16* C = (__bf16*)C2v;
#pragma unroll
      for (int mt = 0; mt < MT; ++mt)
#pragma unroll
        for (int nt = 0; nt < NT; ++nt) {
          int c  = gc + lc0 + nt * 16 + lm;
          int rb = row0 + lr0 + mt * 16 + lq * 4;
          int b  = rb >> 12;
          int s  = rb & 4095;
          bfx4 pk;
#pragma unroll
          for (int i = 0; i < 4; ++i) pk[i] = (__bf16)(acc[mt][nt][i] + bvv[nt]);
          *(bfx4*)(C + ((long)b * HID + c) * SEQ + s) = pk;
        }
    }
  } else if constexpr (MODE == MODE_EXP) {
    __bf16* Ct = L;
    float* rsump = rowsum + (long)z * sR;
#pragma unroll
    for (int mt = 0; mt < MT; ++mt)
#pragma unroll
      for (int i = 0; i < 4; ++i) {
        int rl = lr0 + mt * 16 + lq * 4 + i;
        float rs = 0.f;
#pragma unroll
        for (int nt = 0; nt < NT; ++nt) {
          float e = EXPFN(acc[mt][nt][i]);   // Q pre-scaled: acc = score*log2e
          Ct[rl * CP + lc0 + nt * 16 + lm] = (__bf16)e;
          rs += e;
        }
        rs += __shfl_xor(rs, 1);
        rs += __shfl_xor(rs, 2);
        rs += __shfl_xor(rs, 4);
        rs += __shfl_xor(rs, 8);
        if (lm == 0) atomicAdd(&rsump[row0 + rl], rs);
      }
    __syncthreads();
    __bf16* C = ((__bf16*)C0v) + (long)z * sC;
#pragma unroll
    for (int j = 0; j < TM * TN / 4096; ++j) {
      int s = j * 512 + tid;
      int off = s * 8;
      int r = off / TN, c = off % TN;
      *(bfx8*)(C + (long)(row0 + r) * ldc + col0 + c) = *(const bfx8*)(Ct + r * CP + c);
    }
  } else {  // MODE_DIV: fp32 C-tile roundtrip, vectorized store
    float* Cf = (float*)L;
    const float* rsump = rowsum + (long)z * sR;
#pragma unroll
    for (int mt = 0; mt < MT; ++mt)
#pragma unroll
      for (int i = 0; i < 4; ++i) {
        int rl = lr0 + mt * 16 + lq * 4 + i;
        float inv = 1.f / rsump[row0 + rl];
#pragma unroll
        for (int nt = 0; nt < NT; ++nt)
          Cf[rl * CP + lc0 + nt * 16 + lm] = acc[mt][nt][i] * inv;
      }
    __syncthreads();
    float* C = ((float*)C0v) + (long)z * sC;
#pragma unroll
    for (int j = 0; j < TM * TN / 2048; ++j) {
      int s = j * 512 + tid;
      int off = s * 4;
      int r = off / TN, c = off % TN;
      *(float4*)(C + (long)(row0 + r) * ldc + col0 + c) = *(const float4*)(Cf + r * CP + c);
    }
  }
}

// ---------------------------------------------------------------------------
extern "C" void kernel_launch(void* const* d_in, const int* in_sizes, int n_in,
                              void* d_out, int out_size, void* d_ws, size_t ws_size,
                              hipStream_t stream) {
  (void)in_sizes; (void)n_in; (void)out_size; (void)ws_size;
  const float* X  = (const float*)d_in[0];
  const float* Wq = (const float*)d_in[1];
  const float* bq = (const float*)d_in[2];
  const float* Wk = (const float*)d_in[3];
  const float* bk = (const float*)d_in[4];
  const float* Wv = (const float*)d_in[5];
  const float* bv = (const float*)d_in[6];
  float* out = (float*)d_out;

  // workspace layout (bf16 elements unless noted); total ~193.6 MB
  __bf16* Xb     = (__bf16*)d_ws;                 // 16384*512
  __bf16* Wt     = Xb + (long)MROWS * HID;        // 3*512*512, [g][out][in]
  __bf16* Q      = Wt + 3 * HID * HID;            // 16384*512 (pre-scaled)
  __bf16* Kb     = Q + (long)MROWS * HID;         // 16384*512
  __bf16* Vt     = Kb + (long)MROWS * HID;        // [b][512][4096]
  float*  rowsum = (float*)(Vt + (long)MROWS * HID);  // 16384 fp32
  __bf16* E      = (__bf16*)(rowsum + MROWS);     // [b][4096][4096]

  prep_x_kernel<<<(MROWS * HID) / 1024, 256, 0, stream>>>(X, Xb);
  prep_w_kernel<<<(3 * HID * HID) / 256, 256, 0, stream>>>(Wq, Wk, Wv, Wt);

  (void)hipMemsetAsync(rowsum, 0, MROWS * sizeof(float), stream);

  // fused QKV projection: M=16384, N=1536, K=512
  gemm_bt<MODE_QKV, 128, 128><<<dim3(12, 128, 1), 512, 0, stream>>>(
      Xb, Wt, Q, Kb, Vt, bq, bk, bv, nullptr,
      HID, HID, HID, HID, 0, 0, 0, 0);

  // E = exp2(Q K^T): per batch M=N=4096, K=512 (Q pre-scaled by scale*log2e)
  gemm_bt<MODE_EXP, 128, 128><<<dim3(32, 32, NBATCH), 512, 0, stream>>>(
      Q, Kb, E, nullptr, nullptr, nullptr, nullptr, nullptr, rowsum,
      HID, HID, SEQ, HID, (long)SEQ * HID, (long)SEQ * HID, (long)SEQ * SEQ, SEQ);

  // out = (E @ Vt^T) / rowsum: per batch M=4096, N=512, K=4096; 64x128 tile
  gemm_bt<MODE_DIV, 64, 128><<<dim3(4, 64, NBATCH), 512, 0, stream>>>(
      E, Vt, out, nullptr, nullptr, nullptr, nullptr, nullptr, rowsum,
      SEQ, SEQ, HID, SEQ, (long)SEQ * SEQ, (long)HID * SEQ, (long)SEQ * HID, SEQ);
}

// Round 8
// 332.711 us; speedup vs baseline: 1.1382x; 1.1382x over previous
//
#include <hip/hip_runtime.h>
#include <hip/hip_bf16.h>
#include <math.h>

// ============================================================================
// SelfAttention B=4 S=4096 D=512, fp32 in/out, bf16 MFMA internally.
//
// R8 changes vs R5 (best=327us; R6 VALU-hoist and R7 512-thread both ~+30%
// slower with all pipes <25% busy -> per-iter serial chain = load-issue ->
// vmcnt(0) drain -> barrier -> compute; occupancy & inst-count are not it):
//  - 2-stage software pipeline: double-buffered staging, raw s_barrier +
//    explicit s_waitcnt vmcnt(LPT) (never 0 mid-loop). Next tile's
//    global_load_lds issues before waiting on the current tile, so the
//    drain overlaps a full tile of compute (AITER-style, m139 precedent).
//  - EXP/QKV at BK=32 so dbuf staging (32KB) still fits under the C-tile
//    LDS (34.8KB) -> 4 blocks/CU preserved. Swizzle for 64B rows:
//    chunk ^= (row>>1)&3 (2-way = free). DIV stays BK=64 (dbuf 48KB).
//  - sched_barrier(0) after/before the barriers pins ds_read motion.
//  - Back to R5's 256-thread 2(M)x2(N) wave layout everywhere.
//
// Q pre-scaled by 1/sqrt(512)*log2(e) => EXP epilogue = one v_exp_f32/elem.
// Softmax needs no max-subtraction: |score| <= |q||k|/sqrt(512) ~ 7.5.
// Epilogue stores via padded LDS C-tile roundtrip (CP=TN+8), 16B stores.
// ============================================================================

typedef __bf16 bfx8 __attribute__((ext_vector_type(8)));
typedef __bf16 bfx4 __attribute__((ext_vector_type(4)));
typedef float  fx4  __attribute__((ext_vector_type(4)));

#define HID   512
#define NBATCH 4
#define SEQ   4096
#define MROWS (NBATCH * SEQ)

#if __has_builtin(__builtin_amdgcn_exp2f)
#define EXPFN(x) __builtin_amdgcn_exp2f(x)
#define QSCALE 0.06375871589f   /* (1/sqrt(512)) * log2(e) */
#else
#define EXPFN(x) __expf(x)
#define QSCALE 0.04419417382f   /* 1/sqrt(512) */
#endif

constexpr int MODE_QKV = 0;  // C0=Q(bf16,scaled) C1=K(bf16) C2=Vt(bf16,transposed)
constexpr int MODE_EXP = 2;  // C0 bf16 = exp2(acc), atomic rowsum
constexpr int MODE_DIV = 3;  // C0 fp32 = acc / rowsum[m]

// s_waitcnt imm: vmcnt=n, expcnt=7 (nowait), lgkmcnt=15 (nowait)
constexpr int WVM(int n) { return (n & 15) | ((n >> 4) << 14) | (7 << 4) | (15 << 8); }

// ---------------------------------------------------------------------------
__device__ __forceinline__ void gload_lds16(const __bf16* gsrc, __bf16* ldst) {
  __builtin_amdgcn_global_load_lds(
      (const __attribute__((address_space(1))) unsigned int*)gsrc,
      (__attribute__((address_space(3))) unsigned int*)ldst,
      16, 0, 0);
}

// ---------------------------------------------------------------------------
__global__ void prep_x_kernel(const float* __restrict__ X, __bf16* __restrict__ Xb) {
  int i = (blockIdx.x * 256 + threadIdx.x) * 4;
  const float4 v = *(const float4*)(X + i);
  bfx4 o;
  o[0] = (__bf16)v.x; o[1] = (__bf16)v.y; o[2] = (__bf16)v.z; o[3] = (__bf16)v.w;
  *(bfx4*)(Xb + i) = o;
}

__global__ void prep_w_kernel(const float* __restrict__ Wq, const float* __restrict__ Wk,
                              const float* __restrict__ Wv, __bf16* __restrict__ Wt) {
  int id  = blockIdx.x * 256 + threadIdx.x;   // 0 .. 3*512*512-1
  int g   = id >> 18;
  int rem = id & ((1 << 18) - 1);
  int i   = rem >> 9;          // input dim (row of W)
  int o   = rem & 511;         // output dim (col of W) -- coalesced read
  const float* W = (g == 0) ? Wq : ((g == 1) ? Wk : Wv);
  Wt[(g << 18) + (o << 9) + i] = (__bf16)W[rem];
}

// ---------------------------------------------------------------------------
// C[M,N] = A[M,K] @ B[N,K]^T (+ mode epilogue).  TMxTN tile, BK per template,
// 256 threads = 4 waves 2x2 (wave tile (TM/2)x(TN/2)). Double-buffered
// staging LDS: [buf p][A TM rows | B TN rows][CH chunks of 8 bf16], physical
// chunk = logical chunk ^ ((row>>SH)&(CH-1)). K_ % (2*BK) == 0 assumed.
template <int MODE, int TM, int TN, int BK>
__global__ __launch_bounds__(256)
void gemm_bt(const __bf16* __restrict__ A, const __bf16* __restrict__ B,
             void* __restrict__ C0v, void* __restrict__ C1v, void* __restrict__ C2v,
             const float* __restrict__ b0, const float* __restrict__ b1,
             const float* __restrict__ b2, float* __restrict__ rowsum,
             int lda, int ldb, int ldc, int K_,
             long sA, long sB, long sC, int sR) {
  constexpr int MT  = TM / 32;          // 16-row mfma tiles per wave (M)
  constexpr int NT  = TN / 32;          // 16-col mfma tiles per wave (N)
  constexpr int CH  = BK / 8;           // 16B chunks per row
  constexpr int LCH = (CH == 8) ? 3 : 2;
  constexpr int SH  = (CH == 8) ? 0 : 1;  // swizzle shift (2-way-free mapping)
  constexpr int NKK = BK / 32;          // mfma K-steps per tile
  constexpr int SBE = (TM + TN) * BK;   // staging elems per buffer
  constexpr int CP  = TN + 8;           // padded C-tile stride
  constexpr int CTE = (MODE == MODE_DIV) ? TM * CP * 2 : TM * CP;  // bf16 units
  constexpr int LDSN = (2 * SBE > CTE) ? 2 * SBE : CTE;
  constexpr int LPT_A = TM * CH / 256;  // global_load_lds per thread (A)
  constexpr int LPT_B = TN * CH / 256;
  constexpr int LPT   = LPT_A + LPT_B;
  __shared__ __bf16 L[LDSN];

  const int z = blockIdx.z;
  A += (long)z * sA;
  B += (long)z * sB;

  const int tid  = threadIdx.x;
  const int lane = tid & 63;
  const int w    = tid >> 6;
  const int wm   = w >> 1, wn = w & 1;
  const int lm   = lane & 15, lq = lane >> 4;

  const int row0 = blockIdx.y * TM;
  const int col0 = blockIdx.x * TN;

  const __bf16* Ag = A + (long)row0 * lda;
  const __bf16* Bg = B + (long)col0 * ldb;

  auto issue_tile = [&](int ktv, int p) {
    __bf16* Ad = L + p * SBE;
    __bf16* Bd = Ad + TM * BK;
#pragma unroll
    for (int j = 0; j < LPT_A; ++j) {
      int s = j * 256 + tid;
      int r = s >> LCH, cp = s & (CH - 1);
      int cl = cp ^ ((r >> SH) & (CH - 1));
      gload_lds16(Ag + (long)r * lda + ktv + cl * 8, Ad + j * 2048 + w * 512);
    }
#pragma unroll
    for (int j = 0; j < LPT_B; ++j) {
      int s = j * 256 + tid;
      int r = s >> LCH, cp = s & (CH - 1);
      int cl = cp ^ ((r >> SH) & (CH - 1));
      gload_lds16(Bg + (long)r * ldb + ktv + cl * 8, Bd + j * 2048 + w * 512);
    }
  };

  fx4 acc[MT][NT] = {};
  const int NI = K_ / BK;

  issue_tile(0, 0);
  for (int iter = 0; iter < NI; ++iter) {
    if (iter + 1 < NI) {
      issue_tile((iter + 1) * BK, (iter + 1) & 1);
      __builtin_amdgcn_s_waitcnt(WVM(LPT));   // wait only for CURRENT tile
    } else {
      __builtin_amdgcn_s_waitcnt(WVM(0));
    }
    __builtin_amdgcn_s_barrier();             // all waves' cur loads landed
    __builtin_amdgcn_sched_barrier(0);        // no ds_read hoists above this
    const __bf16* Asp = L + (iter & 1) * SBE;
    const __bf16* Bsp = Asp + TM * BK;
#pragma unroll
    for (int kk = 0; kk < NKK; ++kk) {
      bfx8 af[MT], bfr[NT];
#pragma unroll
      for (int t = 0; t < MT; ++t) {
        int ra = wm * (TM / 2) + t * 16 + lm;
        af[t] = *(const bfx8*)(Asp + ra * BK + (((kk * 4 + lq) ^ ((ra >> SH) & (CH - 1))) << 3));
      }
#pragma unroll
      for (int t = 0; t < NT; ++t) {
        int rb = wn * (TN / 2) + t * 16 + lm;
        bfr[t] = *(const bfx8*)(Bsp + rb * BK + (((kk * 4 + lq) ^ ((rb >> SH) & (CH - 1))) << 3));
      }
#pragma unroll
      for (int mt = 0; mt < MT; ++mt)
#pragma unroll
        for (int nt = 0; nt < NT; ++nt)
          acc[mt][nt] = __builtin_amdgcn_mfma_f32_16x16x32_bf16(af[mt], bfr[nt],
                                                                acc[mt][nt], 0, 0, 0);
    }
    __builtin_amdgcn_sched_barrier(0);        // no ds_read sinks below this
    __builtin_amdgcn_s_barrier();             // readers done before overwrite
  }

  // ---- epilogue ----  C/D layout: col = lane&15, row = (lane>>4)*4 + i
  const int lr0 = wm * (TM / 2);   // + mt*16 + lq*4 + i
  const int lc0 = wn * (TN / 2);   // + nt*16 + lm

  __syncthreads();  // full fence before reusing LDS as C-tile

  if constexpr (MODE == MODE_QKV) {
    const int g   = col0 >> 9;            // 0=Q 1=K 2=V (block-uniform)
    const int gc  = col0 & 511;           // col within the g-th output
    const float* bias = (g == 0) ? b0 : ((g == 1) ? b1 : b2);
    float bvv[NT];
#pragma unroll
    for (int nt = 0; nt < NT; ++nt) bvv[nt] = bias[gc + lc0 + nt * 16 + lm];

    if (g < 2) {  // Q (pre-scaled) / K: LDS C-tile roundtrip, vectorized store
      __bf16* Ct = L;
#pragma unroll
      for (int mt = 0; mt < MT; ++mt)
#pragma unroll
        for (int nt = 0; nt < NT; ++nt)
#pragma unroll
          for (int i = 0; i < 4; ++i) {
            float v = acc[mt][nt][i] + bvv[nt];
            if (g == 0) v *= QSCALE;
            Ct[(lr0 + mt * 16 + lq * 4 + i) * CP + lc0 + nt * 16 + lm] = (__bf16)v;
          }
      __syncthreads();
      __bf16* C = (g == 0) ? (__bf16*)C0v : (__bf16*)C1v;
#pragma unroll
      for (int j = 0; j < TM * TN / 2048; ++j) {
        int s = j * 256 + tid;
        int off = s * 8;
        int r = off / TN, c = off % TN;
        *(bfx8*)(C + (long)(row0 + r) * ldc + gc + c) = *(const bfx8*)(Ct + r * CP + c);
      }
    } else {  // V, transposed: Vt[b][hid][seq], 4 consecutive seq -> 8B store
      __bf16* C = (__bf16*)C2v;
#pragma unroll
      for (int mt = 0; mt < MT; ++mt)
#pragma unroll
        for (int nt = 0; nt < NT; ++nt) {
          int c  = gc + lc0 + nt * 16 + lm;
          int rb = row0 + lr0 + mt * 16 + lq * 4;
          int b  = rb >> 12;
          int s  = rb & 4095;
          bfx4 pk;
#pragma unroll
          for (int i = 0; i < 4; ++i) pk[i] = (__bf16)(acc[mt][nt][i] + bvv[nt]);
          *(bfx4*)(C + ((long)b * HID + c) * SEQ + s) = pk;
        }
    }
  } else if constexpr (MODE == MODE_EXP) {
    __bf16* Ct = L;
    float* rsump = rowsum + (long)z * sR;
#pragma unroll
    for (int mt = 0; mt < MT; ++mt)
#pragma unroll
      for (int i = 0; i < 4; ++i) {
        int rl = lr0 + mt * 16 + lq * 4 + i;
        float rs = 0.f;
#pragma unroll
        for (int nt = 0; nt < NT; ++nt) {
          float e = EXPFN(acc[mt][nt][i]);   // Q pre-scaled: acc = score*log2e
          Ct[rl * CP + lc0 + nt * 16 + lm] = (__bf16)e;
          rs += e;
        }
        rs += __shfl_xor(rs, 1);
        rs += __shfl_xor(rs, 2);
        rs += __shfl_xor(rs, 4);
        rs += __shfl_xor(rs, 8);
        if (lm == 0) atomicAdd(&rsump[row0 + rl], rs);
      }
    __syncthreads();
    __bf16* C = ((__bf16*)C0v) + (long)z * sC;
#pragma unroll
    for (int j = 0; j < TM * TN / 2048; ++j) {
      int s = j * 256 + tid;
      int off = s * 8;
      int r = off / TN, c = off % TN;
      *(bfx8*)(C + (long)(row0 + r) * ldc + col0 + c) = *(const bfx8*)(Ct + r * CP + c);
    }
  } else {  // MODE_DIV: fp32 C-tile roundtrip, vectorized store
    float* Cf = (float*)L;
    const float* rsump = rowsum + (long)z * sR;
#pragma unroll
    for (int mt = 0; mt < MT; ++mt)
#pragma unroll
      for (int i = 0; i < 4; ++i) {
        int rl = lr0 + mt * 16 + lq * 4 + i;
        float inv = 1.f / rsump[row0 + rl];
#pragma unroll
        for (int nt = 0; nt < NT; ++nt)
          Cf[rl * CP + lc0 + nt * 16 + lm] = acc[mt][nt][i] * inv;
      }
    __syncthreads();
    float* C = ((float*)C0v) + (long)z * sC;
#pragma unroll
    for (int j = 0; j < TM * TN / 1024; ++j) {
      int s = j * 256 + tid;
      int off = s * 4;
      int r = off / TN, c = off % TN;
      *(float4*)(C + (long)(row0 + r) * ldc + col0 + c) = *(const float4*)(Cf + r * CP + c);
    }
  }
}

// ---------------------------------------------------------------------------
extern "C" void kernel_launch(void* const* d_in, const int* in_sizes, int n_in,
                              void* d_out, int out_size, void* d_ws, size_t ws_size,
                              hipStream_t stream) {
  (void)in_sizes; (void)n_in; (void)out_size; (void)ws_size;
  const float* X  = (const float*)d_in[0];
  const float* Wq = (const float*)d_in[1];
  const float* bq = (const float*)d_in[2];
  const float* Wk = (const float*)d_in[3];
  const float* bk = (const float*)d_in[4];
  const float* Wv = (const float*)d_in[5];
  const float* bv = (const float*)d_in[6];
  float* out = (float*)d_out;

  // workspace layout (bf16 elements unless noted); total ~193.6 MB
  __bf16* Xb     = (__bf16*)d_ws;                 // 16384*512
  __bf16* Wt     = Xb + (long)MROWS * HID;        // 3*512*512, [g][out][in]
  __bf16* Q      = Wt + 3 * HID * HID;            // 16384*512 (pre-scaled)
  __bf16* Kb     = Q + (long)MROWS * HID;         // 16384*512
  __bf16* Vt     = Kb + (long)MROWS * HID;        // [b][512][4096]
  float*  rowsum = (float*)(Vt + (long)MROWS * HID);  // 16384 fp32
  __bf16* E      = (__bf16*)(rowsum + MROWS);     // [b][4096][4096]

  prep_x_kernel<<<(MROWS * HID) / 1024, 256, 0, stream>>>(X, Xb);
  prep_w_kernel<<<(3 * HID * HID) / 256, 256, 0, stream>>>(Wq, Wk, Wv, Wt);

  (void)hipMemsetAsync(rowsum, 0, MROWS * sizeof(float), stream);

  // fused QKV projection: M=16384, N=1536, K=512 (BK=32, pipelined)
  gemm_bt<MODE_QKV, 128, 128, 32><<<dim3(12, 128, 1), 256, 0, stream>>>(
      Xb, Wt, Q, Kb, Vt, bq, bk, bv, nullptr,
      HID, HID, HID, HID, 0, 0, 0, 0);

  // E = exp2(Q K^T): per batch M=N=4096, K=512 (BK=32, pipelined)
  gemm_bt<MODE_EXP, 128, 128, 32><<<dim3(32, 32, NBATCH), 256, 0, stream>>>(
      Q, Kb, E, nullptr, nullptr, nullptr, nullptr, nullptr, rowsum,
      HID, HID, SEQ, HID, (long)SEQ * HID, (long)SEQ * HID, (long)SEQ * SEQ, SEQ);

  // out = (E @ Vt^T) / rowsum: per batch M=4096, N=512, K=4096 (BK=64)
  gemm_bt<MODE_DIV, 64, 128, 64><<<dim3(4, 64, NBATCH), 256, 0, stream>>>(
      E, Vt, out, nullptr, nullptr, nullptr, nullptr, nullptr, rowsum,
      SEQ, SEQ, HID, SEQ, (long)SEQ * SEQ, (long)HID * SEQ, (long)SEQ * HID, SEQ);
}